// Round 5
// baseline (12853.047 us; speedup 1.0000x reference)
//
#include <hip/hip_runtime.h>
#include <hip/hip_cooperative_groups.h>
#include <hip/hip_fp16.h>
#include <cmath>

namespace cg = cooperative_groups;

#define Bsz 256
#define Tn  100
#define Fd  128
#define Hd  512
#define Od  128
#define Md  512

struct __align__(16) half8 { __half2 h2[4]; };

__device__ __forceinline__ float sigf(float x) { return 1.0f / (1.0f + __expf(-x)); }

// Precompute: WlsTh (fp16, [768][128]), bqs, memTh (fp16 [128][512]), memh (fp16 copy of memory),
// WfcT (fp32 [512][128], WfcT[j][o] = Wfc[o][j])
__global__ void kPre(const float* __restrict__ Wq, const float* __restrict__ bq,
                     const float* __restrict__ bfc, const float* __restrict__ Wfc,
                     const float* __restrict__ memory,
                     __half* __restrict__ WlsTh, __half* __restrict__ memTh,
                     __half* __restrict__ memh,
                     float* __restrict__ WfcT, float* __restrict__ bqs)
{
    int bid = blockIdx.x, tid = threadIdx.x;
    if (bid < 768) {
        if (tid < 128) {
            int k = bid, f = tid;
            float v;
            if (k < 256) v = Wq[f * 384 + k];
            else {
                int kk = k - 256;
                float s = 0.f;
                for (int o = 0; o < 128; ++o) s += Wfc[o * 512 + kk] * Wq[f * 384 + 256 + o];
                v = s;
            }
            WlsTh[k * 128 + f] = __float2half(v);
        }
    } else if (bid == 768) {
        if (tid < 128) {
            float s = bq[tid];
            for (int o = 0; o < 128; ++o) s += bfc[o] * Wq[tid * 384 + 256 + o];
            bqs[tid] = s;
        }
    } else if (bid < 897) {
        int f = bid - 769;
        int m = tid;
        memTh[f * 512 + m] = __float2half(memory[m * 128 + f]);
        m = tid + 256;
        memTh[f * 512 + m] = __float2half(memory[m * 128 + f]);
    } else if (bid < 1409) {
        int j = bid - 897;
        if (tid < 128) WfcT[j * 128 + tid] = Wfc[tid * 512 + j];
    } else {
        int base = (bid - 1409) * 1024 + tid * 4;
        #pragma unroll
        for (int e = 0; e < 4; ++e) memh[base + e] = __float2half(memory[base + e]);
    }
}

// Persistent cooperative kernel, 256 WGs x 1024 threads (16 waves/CU).
__launch_bounds__(1024, 4)
__global__ void kMain(const float* __restrict__ input, const float* __restrict__ Xmean,
                      const float* __restrict__ Wgz, const float* __restrict__ bgz,
                      const float* __restrict__ Wgzp, const float* __restrict__ bgzp,
                      const float* __restrict__ Wih, const float* __restrict__ Whh,
                      const float* __restrict__ bih, const float* __restrict__ bhh,
                      const float* __restrict__ bfc,
                      float* __restrict__ h0, float* __restrict__ h1,
                      float* __restrict__ gdg,
                      const __half* __restrict__ WlsTh, const __half* __restrict__ memTh,
                      const __half* __restrict__ memh,
                      const float* __restrict__ WfcT, const float* __restrict__ bqs,
                      float* __restrict__ out)
{
    __shared__ __align__(16) float w_s[32 * 644];   // 82.4 KB: [32 wrows][640+4] fp32
    __shared__ __align__(16) float sbuf[16640];     // 66.5 KB: phaseA red / a_s / psum
    __shared__ __align__(16) float hs[512];
    __shared__ __align__(16) float zzs[256];
    __shared__ __align__(16) float lss[128];
    __shared__ __align__(16) float scs[512];
    __shared__ __align__(16) float swred[32];

    cg::grid_group grid = cg::this_grid();
    const int tid = threadIdx.x;
    const int wg  = blockIdx.x;

    // ---- phase-B geometry ----
    const int b0 = (wg >> 6) * 64;
    const int j0 = (wg & 63) * 8;
    const int sg = tid >> 7;        // 0..7 K-split subgroup
    const int st = tid & 127;
    const int ti = st >> 3;         // 0..15
    const int tj = st & 7;          // 0..7

    // W slice -> LDS once. wrow nl = gate*8 + jl -> n = gate*512 + j0 + jl
    for (int idx = tid; idx < 32 * 644; idx += 1024) {
        int nl = idx / 644, kk = idx - nl * 644;
        float v = 0.f;
        if (kk < 640) {
            int n = (nl >> 3) * 512 + j0 + (nl & 7);
            v = (kk < 128) ? Wih[n * 128 + kk] : Whh[n * 512 + (kk - 128)];
        }
        w_s[idx] = v;
    }

    // epilogue-thread state (tid<512): one (bl,jl) pair each
    float bs0 = 0.f, bs1 = 0.f, bs2 = 0.f, bs3 = 0.f, creg = 0.f;
    if (tid < 512) {
        int jl = tid & 7, jcol = j0 + jl;
        bs0 = bih[jcol]        + bhh[jcol];
        bs1 = bih[512 + jcol]  + bhh[512 + jcol];
        bs2 = bih[1024 + jcol] + bhh[1024 + jcol];
        bs3 = bih[1536 + jcol] + bhh[1536 + jcol];
    }
    // phase-A decay params
    float wvp = 0.f, bvp = 0.f;
    if (tid < 256) {
        int f = tid & 127;
        if (tid < 128) { wvp = Wgz[f * 129];  bvp = bgz[f]; }
        else           { wvp = Wgzp[f * 129]; bvp = bgzp[f]; }
    }
    __syncthreads();

    const half8* WlsTh8 = (const half8*)WlsTh;
    const half8* memTh8 = (const half8*)memTh;
    const half8* memh8  = (const half8*)memh;
    float4* sb4 = (float4*)sbuf;
    const float4* ws4 = (const float4*)w_s;
    float4* gd4 = (float4*)gdg;

    float* hcur = h0;
    float* hnxt = h1;

    for (int t = 0; t < Tn; ++t) {
        // ================= phase A (row b = wg) =================
        if (tid < 512) hs[tid] = hcur[wg * 512 + tid];
        if (tid < 256) {
            int f = tid & 127;
            const float* basep = input + (size_t)wg * 6 * Tn * Fd + t * Fd;
            float x    = basep[0 * Tn * Fd + f];
            float mask = basep[2 * Tn * Fd + f];
            float xm   = Xmean[t * Fd + f];
            float xl, dl;
            if (tid < 128) { xl = basep[1 * Tn * Fd + f]; dl = basep[3 * Tn * Fd + f]; }
            else           { xl = basep[4 * Tn * Fd + f]; dl = basep[5 * Tn * Fd + f]; }
            float d = __expf(-fmaxf(dl * wvp + bvp, 0.f));
            zzs[tid] = mask * x + (1.f - mask) * (d * xl + (1.f - d) * xm);
        }
        __syncthreads();
        // ---- ls partials: 64 k-chunks x 16 f-octs ----
        {
            int fg = tid & 15, kh = tid >> 4;
            float a[8] = {0,0,0,0,0,0,0,0};
            int ks = kh * 12;
            #pragma unroll 4
            for (int kk = 0; kk < 12; ++kk) {
                int k = ks + kk;
                float v = (k < 256) ? zzs[k] : hs[k - 256];
                half8 w = WlsTh8[k * 16 + fg];
                float2 p0 = __half22float2(w.h2[0]), p1 = __half22float2(w.h2[1]);
                float2 p2 = __half22float2(w.h2[2]), p3 = __half22float2(w.h2[3]);
                a[0] += v * p0.x; a[1] += v * p0.y; a[2] += v * p1.x; a[3] += v * p1.y;
                a[4] += v * p2.x; a[5] += v * p2.y; a[6] += v * p3.x; a[7] += v * p3.y;
            }
            int base = kh * 32 + fg * 2;
            sb4[base]     = make_float4(a[0], a[1], a[2], a[3]);
            sb4[base + 1] = make_float4(a[4], a[5], a[6], a[7]);
        }
        __syncthreads();
        if (tid < 512) {
            int f = tid & 127, q = tid >> 7;
            float s = 0.f;
            #pragma unroll
            for (int u = 0; u < 16; ++u) s += sbuf[(q * 16 + u) * 128 + f];
            sbuf[8192 + q * 128 + f] = s;
        }
        __syncthreads();
        if (tid < 128)
            lss[tid] = bqs[tid] + sbuf[8192 + tid] + sbuf[8320 + tid] + sbuf[8448 + tid] + sbuf[8576 + tid];
        __syncthreads();
        // ---- scores: 16 f-chunks x 64 m-octs ----
        {
            int mg = tid & 63, fh = tid >> 6;
            float a[8] = {0,0,0,0,0,0,0,0};
            int fs = fh * 8;
            #pragma unroll
            for (int ff = 0; ff < 8; ++ff) {
                float v = lss[fs + ff];
                half8 w = memTh8[(fs + ff) * 64 + mg];
                float2 p0 = __half22float2(w.h2[0]), p1 = __half22float2(w.h2[1]);
                float2 p2 = __half22float2(w.h2[2]), p3 = __half22float2(w.h2[3]);
                a[0] += v * p0.x; a[1] += v * p0.y; a[2] += v * p1.x; a[3] += v * p1.y;
                a[4] += v * p2.x; a[5] += v * p2.y; a[6] += v * p3.x; a[7] += v * p3.y;
            }
            int base = fh * 128 + mg * 2;
            sb4[base]     = make_float4(a[0], a[1], a[2], a[3]);
            sb4[base + 1] = make_float4(a[4], a[5], a[6], a[7]);
        }
        __syncthreads();
        if (tid < 512) {
            float s = 0.f;
            #pragma unroll
            for (int u = 0; u < 16; ++u) s += sbuf[u * 512 + tid];
            scs[tid] = s;
        }
        __syncthreads();
        // ---- softmax over 512 ----
        float vsc = scs[tid & 511];
        float mv = vsc;
        #pragma unroll
        for (int off = 32; off > 0; off >>= 1) mv = fmaxf(mv, __shfl_xor(mv, off));
        if ((tid & 63) == 0) swred[tid >> 6] = mv;
        __syncthreads();
        float mx = swred[0];
        #pragma unroll
        for (int u = 1; u < 16; ++u) mx = fmaxf(mx, swred[u]);
        float ev = __expf(vsc - mx);
        if (tid < 512) scs[tid] = ev;
        float sv = (tid < 512) ? ev : 0.f;
        #pragma unroll
        for (int off = 32; off > 0; off >>= 1) sv += __shfl_xor(sv, off);
        if ((tid & 63) == 0) swred[16 + (tid >> 6)] = sv;
        __syncthreads();
        float tot = 0.f;
        #pragma unroll
        for (int u = 0; u < 16; ++u) tot += swred[16 + u];
        float inv = 1.f / tot;
        __syncthreads();
        // ---- gd = attn @ memory: 64 m-chunks x 16 f-octs ----
        {
            int fg = tid & 15, mh = tid >> 4;
            float a[8] = {0,0,0,0,0,0,0,0};
            int ms = mh * 8;
            #pragma unroll
            for (int mm = 0; mm < 8; ++mm) {
                float p = scs[ms + mm];
                half8 w = memh8[(ms + mm) * 16 + fg];
                float2 p0 = __half22float2(w.h2[0]), p1 = __half22float2(w.h2[1]);
                float2 p2 = __half22float2(w.h2[2]), p3 = __half22float2(w.h2[3]);
                a[0] += p * p0.x; a[1] += p * p0.y; a[2] += p * p1.x; a[3] += p * p1.y;
                a[4] += p * p2.x; a[5] += p * p2.y; a[6] += p * p3.x; a[7] += p * p3.y;
            }
            int base = mh * 32 + fg * 2;
            sb4[base]     = make_float4(a[0], a[1], a[2], a[3]);
            sb4[base + 1] = make_float4(a[4], a[5], a[6], a[7]);
        }
        __syncthreads();
        if (tid < 512) {
            int f = tid & 127, q = tid >> 7;
            float s = 0.f;
            #pragma unroll
            for (int u = 0; u < 16; ++u) s += sbuf[(q * 16 + u) * 128 + f];
            sbuf[8192 + q * 128 + f] = s;
        }
        __syncthreads();
        if (tid < 128)
            gdg[wg * 128 + tid] = (sbuf[8192 + tid] + sbuf[8320 + tid] + sbuf[8448 + tid] + sbuf[8576 + tid]) * inv;

        grid.sync();
        // ================= phase B =================
        {
            const float4* gdc4 = (const float4*)gdg;
            const float4* hc4  = (const float4*)hcur;
            float4* as4 = sb4 + sg * 320;   // [64][5] float4 per subgroup

            float4 pf0, pf1;
            {
                int r0 = st >> 2, q0 = st & 3;
                int k4 = sg * 20 + q0;
                pf0 = (k4 < 32) ? gdc4[(b0 + r0) * 32 + k4] : hc4[(b0 + r0) * 128 + (k4 - 32)];
                int idx = st + 128; int r1 = idx >> 2, q1 = idx & 3;
                k4 = sg * 20 + q1;
                pf1 = (k4 < 32) ? gdc4[(b0 + r1) * 32 + k4] : hc4[(b0 + r1) * 128 + (k4 - 32)];
            }
            float acc[4][4] = {};
            for (int cc = 0; cc < 5; ++cc) {
                {
                    int r0 = st >> 2, q0 = st & 3;
                    as4[r0 * 5 + q0] = pf0;
                    int idx = st + 128; int r1 = idx >> 2, q1 = idx & 3;
                    as4[r1 * 5 + q1] = pf1;
                }
                __syncthreads();
                if (cc < 4) {
                    int r0 = st >> 2, q0 = st & 3;
                    int k4 = sg * 20 + (cc + 1) * 4 + q0;
                    pf0 = (k4 < 32) ? gdc4[(b0 + r0) * 32 + k4] : hc4[(b0 + r0) * 128 + (k4 - 32)];
                    int idx = st + 128; int r1 = idx >> 2, q1 = idx & 3;
                    k4 = sg * 20 + (cc + 1) * 4 + q1;
                    pf1 = (k4 < 32) ? gdc4[(b0 + r1) * 32 + k4] : hc4[(b0 + r1) * 128 + (k4 - 32)];
                }
                #pragma unroll
                for (int kq = 0; kq < 4; ++kq) {
                    int k4 = sg * 20 + cc * 4 + kq;
                    float4 w0 = ws4[(tj)      * 161 + k4];
                    float4 w1 = ws4[(tj + 8)  * 161 + k4];
                    float4 w2 = ws4[(tj + 16) * 161 + k4];
                    float4 w3 = ws4[(tj + 24) * 161 + k4];
                    #pragma unroll
                    for (int c = 0; c < 4; ++c) {
                        float4 a = as4[(ti + 16 * c) * 5 + kq];
                        acc[c][0] += a.x * w0.x + a.y * w0.y + a.z * w0.z + a.w * w0.w;
                        acc[c][1] += a.x * w1.x + a.y * w1.y + a.z * w1.z + a.w * w1.w;
                        acc[c][2] += a.x * w2.x + a.y * w2.y + a.z * w2.z + a.w * w2.w;
                        acc[c][3] += a.x * w3.x + a.y * w3.y + a.z * w3.z + a.w * w3.w;
                    }
                }
                __syncthreads();
            }
            // psum[sg][wrow*65 + bl]
            #pragma unroll
            for (int c = 0; c < 4; ++c)
                #pragma unroll
                for (int g = 0; g < 4; ++g)
                    sbuf[sg * 2080 + (tj + 8 * g) * 65 + (ti + 16 * c)] = acc[c][g];
            __syncthreads();
            if (tid < 512) {
                int bl = tid >> 3, jl = tid & 7;
                float gsum[4];
                #pragma unroll
                for (int gate = 0; gate < 4; ++gate) {
                    int wrow = gate * 8 + jl;
                    float s = 0.f;
                    #pragma unroll
                    for (int s8 = 0; s8 < 8; ++s8) s += sbuf[s8 * 2080 + wrow * 65 + bl];
                    gsum[gate] = s;
                }
                float gi = gsum[0] + bs0, gf = gsum[1] + bs1;
                float gg = gsum[2] + bs2, go = gsum[3] + bs3;
                float cn = sigf(gf) * creg + sigf(gi) * tanhf(gg);
                float hn = sigf(go) * tanhf(cn);
                creg = cn;
                hnxt[(b0 + bl) * 512 + (j0 + jl)] = hn;
            }
        }
        grid.sync();
        float* tsw = hcur; hcur = hnxt; hnxt = tsw;
    }

    // ================= final out = h @ WfcT + bfc =================
    {
        if (tid < 512) hs[tid] = hcur[wg * 512 + tid];
        __syncthreads();
        int fg = tid & 31, fh = tid >> 5;
        const float4* WfcT4 = (const float4*)WfcT;
        float4 acc = {0.f, 0.f, 0.f, 0.f};
        int js = fh * 16;
        #pragma unroll
        for (int jj = 0; jj < 16; ++jj) {
            float hv = hs[js + jj];
            float4 w = WfcT4[(js + jj) * 32 + fg];
            acc.x += hv * w.x; acc.y += hv * w.y; acc.z += hv * w.z; acc.w += hv * w.w;
        }
        sb4[fh * 32 + fg] = acc;
        __syncthreads();
        if (tid < 32) {
            const float4* bfc4 = (const float4*)bfc;
            float4 s = bfc4[tid];
            #pragma unroll
            for (int u = 0; u < 32; ++u) {
                float4 r = sb4[u * 32 + tid];
                s.x += r.x; s.y += r.y; s.z += r.z; s.w += r.w;
            }
            ((float4*)out)[wg * 32 + tid] = s;
        }
    }
}

extern "C" void kernel_launch(void* const* d_in, const int* in_sizes, int n_in,
                              void* d_out, int out_size, void* d_ws, size_t ws_size,
                              hipStream_t stream)
{
    const float* input  = (const float*)d_in[0];
    const float* Xmean  = (const float*)d_in[1];
    const float* Wgz    = (const float*)d_in[2];
    const float* bgz    = (const float*)d_in[3];
    const float* Wgzp   = (const float*)d_in[4];
    const float* bgzp   = (const float*)d_in[5];
    const float* Wq     = (const float*)d_in[6];
    const float* bq     = (const float*)d_in[7];
    const float* memory = (const float*)d_in[8];
    const float* Wih    = (const float*)d_in[9];
    const float* Whh    = (const float*)d_in[10];
    const float* bih    = (const float*)d_in[11];
    const float* bhh    = (const float*)d_in[12];
    const float* Wfc    = (const float*)d_in[13];
    const float* bfc    = (const float*)d_in[14];
    float* outp = (float*)d_out;

    float* ws    = (float*)d_ws;
    float* h0    = ws;                    // 131072 f
    float* h1    = h0 + 131072;           // 131072 f
    float* gdp   = h1 + 131072;           // 32768 f
    float* WfcT  = gdp + 32768;           // 65536 f
    float* bqs   = WfcT + 65536;          // 128 f
    __half* WlsTh = (__half*)(bqs + 128);         // 98304 h = 49152 f
    __half* memTh = (__half*)(bqs + 128 + 49152); // 65536 h = 32768 f
    __half* memh  = (__half*)(bqs + 128 + 49152 + 32768); // 65536 h

    hipMemsetAsync(h0, 0, 131072 * sizeof(float), stream);
    kPre<<<1473, 256, 0, stream>>>(Wq, bq, bfc, Wfc, memory, WlsTh, memTh, memh, WfcT, bqs);

    void* args[] = {
        (void*)&input, (void*)&Xmean, (void*)&Wgz, (void*)&bgz, (void*)&Wgzp, (void*)&bgzp,
        (void*)&Wih, (void*)&Whh, (void*)&bih, (void*)&bhh, (void*)&bfc,
        (void*)&h0, (void*)&h1, (void*)&gdp, (void*)&WlsTh, (void*)&memTh, (void*)&memh,
        (void*)&WfcT, (void*)&bqs, (void*)&outp
    };
    hipLaunchCooperativeKernel((void*)kMain, dim3(256), dim3(1024), args, 0, stream);
}

// Round 6
// 9554.808 us; speedup vs baseline: 1.3452x; 1.3452x over previous
//
#include <hip/hip_runtime.h>
#include <hip/hip_cooperative_groups.h>
#include <hip/hip_fp16.h>
#include <cmath>

namespace cg = cooperative_groups;

#define Bsz 256
#define Tn  100
#define Fd  128
#define Hd  512
#define Od  128
#define Md  512

struct __align__(16) half8 { __half2 h2[4]; };

__device__ __forceinline__ float sigf(float x) { return 1.0f / (1.0f + __expf(-x)); }

// Precompute: WlsTh (fp16, [768][128]), bqs, memTh (fp16 [128][512]), memh (fp16 copy of memory),
// WfcT (fp32 [512][128], WfcT[j][o] = Wfc[o][j])
__global__ void kPre(const float* __restrict__ Wq, const float* __restrict__ bq,
                     const float* __restrict__ bfc, const float* __restrict__ Wfc,
                     const float* __restrict__ memory,
                     __half* __restrict__ WlsTh, __half* __restrict__ memTh,
                     __half* __restrict__ memh,
                     float* __restrict__ WfcT, float* __restrict__ bqs)
{
    int bid = blockIdx.x, tid = threadIdx.x;
    if (bid < 768) {
        if (tid < 128) {
            int k = bid, f = tid;
            float v;
            if (k < 256) v = Wq[f * 384 + k];
            else {
                int kk = k - 256;
                float s = 0.f;
                for (int o = 0; o < 128; ++o) s += Wfc[o * 512 + kk] * Wq[f * 384 + 256 + o];
                v = s;
            }
            WlsTh[k * 128 + f] = __float2half(v);
        }
    } else if (bid == 768) {
        if (tid < 128) {
            float s = bq[tid];
            for (int o = 0; o < 128; ++o) s += bfc[o] * Wq[tid * 384 + 256 + o];
            bqs[tid] = s;
        }
    } else if (bid < 897) {
        int f = bid - 769;
        int m = tid;
        memTh[f * 512 + m] = __float2half(memory[m * 128 + f]);
        m = tid + 256;
        memTh[f * 512 + m] = __float2half(memory[m * 128 + f]);
    } else if (bid < 1409) {
        int j = bid - 897;
        if (tid < 128) WfcT[j * 128 + tid] = Wfc[tid * 512 + j];
    } else {
        int base = (bid - 1409) * 1024 + tid * 4;
        #pragma unroll
        for (int e = 0; e < 4; ++e) memh[base + e] = __float2half(memory[base + e]);
    }
}

// Persistent cooperative kernel, 256 WGs x 512 threads (8 waves/CU, VGPR cap 256 -> no spills).
__launch_bounds__(512, 2)
__global__ void kMain(const float* __restrict__ input, const float* __restrict__ Xmean,
                      const float* __restrict__ Wgz, const float* __restrict__ bgz,
                      const float* __restrict__ Wgzp, const float* __restrict__ bgzp,
                      const float* __restrict__ Wih, const float* __restrict__ Whh,
                      const float* __restrict__ bih, const float* __restrict__ bhh,
                      const float* __restrict__ bfc,
                      float* __restrict__ h0, float* __restrict__ h1,
                      float* __restrict__ gdg,
                      const __half* __restrict__ WlsTh, const __half* __restrict__ memTh,
                      const __half* __restrict__ memh,
                      const float* __restrict__ WfcT, const float* __restrict__ bqs,
                      float* __restrict__ out)
{
    __shared__ __align__(16) float w_s[32 * 644];   // 82.4 KB
    __shared__ __align__(16) float sbuf[16640];     // 66.5 KB
    __shared__ __align__(16) float hs[512];
    __shared__ __align__(16) float zzs[256];
    __shared__ __align__(16) float lss[128];
    __shared__ __align__(16) float scs[512];
    __shared__ __align__(16) float swred[32];

    cg::grid_group grid = cg::this_grid();
    const int tid = threadIdx.x;
    const int wg  = blockIdx.x;

    // ---- phase-B geometry: 8 subgroups x 64 threads ----
    const int b0 = (wg >> 6) * 64;
    const int j0 = (wg & 63) * 8;
    const int sg = tid >> 6;        // 0..7 (K-split, K=80 each)
    const int st = tid & 63;
    const int ti = st >> 3;         // 0..7 -> rows ti + 8c
    const int tj = st & 7;          // 0..7 -> wrows tj + 8g

    // W slice -> LDS once
    for (int idx = tid; idx < 32 * 644; idx += 512) {
        int nl = idx / 644, kk = idx - nl * 644;
        float v = 0.f;
        if (kk < 640) {
            int n = (nl >> 3) * 512 + j0 + (nl & 7);
            v = (kk < 128) ? Wih[n * 128 + kk] : Whh[n * 512 + (kk - 128)];
        }
        w_s[idx] = v;
    }

    // epilogue-thread state: one (bl, jl) pair each (512 = 64x8)
    float bs0, bs1, bs2, bs3, creg = 0.f;
    {
        int jl = tid & 7, jcol = j0 + jl;
        bs0 = bih[jcol]        + bhh[jcol];
        bs1 = bih[512 + jcol]  + bhh[512 + jcol];
        bs2 = bih[1024 + jcol] + bhh[1024 + jcol];
        bs3 = bih[1536 + jcol] + bhh[1536 + jcol];
    }
    float wvp = 0.f, bvp = 0.f;
    if (tid < 256) {
        int f = tid & 127;
        if (tid < 128) { wvp = Wgz[f * 129];  bvp = bgz[f]; }
        else           { wvp = Wgzp[f * 129]; bvp = bgzp[f]; }
    }
    __syncthreads();

    const half8* WlsTh8 = (const half8*)WlsTh;
    const half8* memTh8 = (const half8*)memTh;
    const half8* memh8  = (const half8*)memh;
    float4* sb4 = (float4*)sbuf;
    const float4* ws4 = (const float4*)w_s;

    float* hcur = h0;
    float* hnxt = h1;

    for (int t = 0; t < Tn; ++t) {
        // ================= phase A (row b = wg) =================
        hs[tid] = hcur[wg * 512 + tid];
        if (tid < 256) {
            int f = tid & 127;
            const float* basep = input + (size_t)wg * 6 * Tn * Fd + t * Fd;
            float x    = basep[0 * Tn * Fd + f];
            float mask = basep[2 * Tn * Fd + f];
            float xm   = Xmean[t * Fd + f];
            float xl, dl;
            if (tid < 128) { xl = basep[1 * Tn * Fd + f]; dl = basep[3 * Tn * Fd + f]; }
            else           { xl = basep[4 * Tn * Fd + f]; dl = basep[5 * Tn * Fd + f]; }
            float d = __expf(-fmaxf(dl * wvp + bvp, 0.f));
            zzs[tid] = mask * x + (1.f - mask) * (d * xl + (1.f - d) * xm);
        }
        __syncthreads();
        // ---- ls partials: 32 k-chunks (24 k each) x 16 f-octs ----
        {
            int fg = tid & 15, kh = tid >> 4;
            float a[8] = {0,0,0,0,0,0,0,0};
            int ks = kh * 24;
            #pragma unroll 4
            for (int kk = 0; kk < 24; ++kk) {
                int k = ks + kk;
                float v = (k < 256) ? zzs[k] : hs[k - 256];
                half8 w = WlsTh8[k * 16 + fg];
                float2 p0 = __half22float2(w.h2[0]), p1 = __half22float2(w.h2[1]);
                float2 p2 = __half22float2(w.h2[2]), p3 = __half22float2(w.h2[3]);
                a[0] += v * p0.x; a[1] += v * p0.y; a[2] += v * p1.x; a[3] += v * p1.y;
                a[4] += v * p2.x; a[5] += v * p2.y; a[6] += v * p3.x; a[7] += v * p3.y;
            }
            int base = kh * 32 + fg * 2;
            sb4[base]     = make_float4(a[0], a[1], a[2], a[3]);
            sb4[base + 1] = make_float4(a[4], a[5], a[6], a[7]);
        }
        __syncthreads();
        {
            int f = tid & 127, q = tid >> 7;   // q 0..3, sums 8 rows each
            float s = 0.f;
            #pragma unroll
            for (int u = 0; u < 8; ++u) s += sbuf[(q * 8 + u) * 128 + f];
            sbuf[8192 + q * 128 + f] = s;
        }
        __syncthreads();
        if (tid < 128)
            lss[tid] = bqs[tid] + sbuf[8192 + tid] + sbuf[8320 + tid] + sbuf[8448 + tid] + sbuf[8576 + tid];
        __syncthreads();
        // ---- scores: 8 f-chunks (16 f each) x 64 m-octs ----
        {
            int mg = tid & 63, fh = tid >> 6;
            float a[8] = {0,0,0,0,0,0,0,0};
            int fs = fh * 16;
            #pragma unroll 4
            for (int ff = 0; ff < 16; ++ff) {
                float v = lss[fs + ff];
                half8 w = memTh8[(fs + ff) * 64 + mg];
                float2 p0 = __half22float2(w.h2[0]), p1 = __half22float2(w.h2[1]);
                float2 p2 = __half22float2(w.h2[2]), p3 = __half22float2(w.h2[3]);
                a[0] += v * p0.x; a[1] += v * p0.y; a[2] += v * p1.x; a[3] += v * p1.y;
                a[4] += v * p2.x; a[5] += v * p2.y; a[6] += v * p3.x; a[7] += v * p3.y;
            }
            int base = fh * 128 + mg * 2;
            sb4[base]     = make_float4(a[0], a[1], a[2], a[3]);
            sb4[base + 1] = make_float4(a[4], a[5], a[6], a[7]);
        }
        __syncthreads();
        {
            float s = 0.f;
            #pragma unroll
            for (int u = 0; u < 8; ++u) s += sbuf[u * 512 + tid];
            scs[tid] = s;
        }
        __syncthreads();
        // ---- softmax over 512 (1 elem/thread) ----
        float vsc = scs[tid];
        float mv = vsc;
        #pragma unroll
        for (int off = 32; off > 0; off >>= 1) mv = fmaxf(mv, __shfl_xor(mv, off));
        if ((tid & 63) == 0) swred[tid >> 6] = mv;
        __syncthreads();
        float mx = swred[0];
        #pragma unroll
        for (int u = 1; u < 8; ++u) mx = fmaxf(mx, swred[u]);
        float ev = __expf(vsc - mx);
        scs[tid] = ev;
        float sv = ev;
        #pragma unroll
        for (int off = 32; off > 0; off >>= 1) sv += __shfl_xor(sv, off);
        if ((tid & 63) == 0) swred[8 + (tid >> 6)] = sv;
        __syncthreads();
        float tot = 0.f;
        #pragma unroll
        for (int u = 0; u < 8; ++u) tot += swred[8 + u];
        float inv = 1.f / tot;
        // ---- gd = attn @ memory: 32 m-chunks (16 m each) x 16 f-octs ----
        {
            int fg = tid & 15, mh = tid >> 4;
            float a[8] = {0,0,0,0,0,0,0,0};
            int ms = mh * 16;
            #pragma unroll 4
            for (int mm = 0; mm < 16; ++mm) {
                float p = scs[ms + mm];
                half8 w = memh8[(ms + mm) * 16 + fg];
                float2 p0 = __half22float2(w.h2[0]), p1 = __half22float2(w.h2[1]);
                float2 p2 = __half22float2(w.h2[2]), p3 = __half22float2(w.h2[3]);
                a[0] += p * p0.x; a[1] += p * p0.y; a[2] += p * p1.x; a[3] += p * p1.y;
                a[4] += p * p2.x; a[5] += p * p2.y; a[6] += p * p3.x; a[7] += p * p3.y;
            }
            __syncthreads();   // scores-stage reads of sbuf done; safe to overwrite
            int base = mh * 32 + fg * 2;
            sb4[base]     = make_float4(a[0], a[1], a[2], a[3]);
            sb4[base + 1] = make_float4(a[4], a[5], a[6], a[7]);
        }
        __syncthreads();
        {
            int f = tid & 127, q = tid >> 7;
            float s = 0.f;
            #pragma unroll
            for (int u = 0; u < 8; ++u) s += sbuf[(q * 8 + u) * 128 + f];
            sbuf[8192 + q * 128 + f] = s;
        }
        __syncthreads();
        if (tid < 128)
            gdg[wg * 128 + tid] = (sbuf[8192 + tid] + sbuf[8320 + tid] + sbuf[8448 + tid] + sbuf[8576 + tid]) * inv;

        grid.sync();
        // ================= phase B =================
        {
            const float4* gdc4 = (const float4*)gdg;
            const float4* hc4  = (const float4*)hcur;
            float4* as4 = sb4 + sg * 320;   // [64 rows][5 f4] per subgroup

            float4 pf[4];
            #pragma unroll
            for (int u = 0; u < 4; ++u) {
                int e = st + 64 * u; int r = e >> 2, q = e & 3;
                int k4 = sg * 20 + q;
                pf[u] = (k4 < 32) ? gdc4[(b0 + r) * 32 + k4] : hc4[(b0 + r) * 128 + (k4 - 32)];
            }
            float acc[8][4] = {};
            for (int cc = 0; cc < 5; ++cc) {
                #pragma unroll
                for (int u = 0; u < 4; ++u) {
                    int e = st + 64 * u; int r = e >> 2, q = e & 3;
                    as4[r * 5 + q] = pf[u];
                }
                __syncthreads();
                if (cc < 4) {
                    #pragma unroll
                    for (int u = 0; u < 4; ++u) {
                        int e = st + 64 * u; int r = e >> 2, q = e & 3;
                        int k4 = sg * 20 + (cc + 1) * 4 + q;
                        pf[u] = (k4 < 32) ? gdc4[(b0 + r) * 32 + k4] : hc4[(b0 + r) * 128 + (k4 - 32)];
                    }
                }
                #pragma unroll
                for (int kq = 0; kq < 4; ++kq) {
                    int k4 = sg * 20 + cc * 4 + kq;
                    float4 w0 = ws4[(tj)      * 161 + k4];
                    float4 w1 = ws4[(tj + 8)  * 161 + k4];
                    float4 w2 = ws4[(tj + 16) * 161 + k4];
                    float4 w3 = ws4[(tj + 24) * 161 + k4];
                    #pragma unroll
                    for (int c = 0; c < 8; ++c) {
                        float4 a = as4[(ti + 8 * c) * 5 + kq];
                        acc[c][0] += a.x * w0.x + a.y * w0.y + a.z * w0.z + a.w * w0.w;
                        acc[c][1] += a.x * w1.x + a.y * w1.y + a.z * w1.z + a.w * w1.w;
                        acc[c][2] += a.x * w2.x + a.y * w2.y + a.z * w2.z + a.w * w2.w;
                        acc[c][3] += a.x * w3.x + a.y * w3.y + a.z * w3.z + a.w * w3.w;
                    }
                }
                __syncthreads();
            }
            // psum[sg][wrow*65 + bl]
            #pragma unroll
            for (int c = 0; c < 8; ++c)
                #pragma unroll
                for (int g = 0; g < 4; ++g)
                    sbuf[sg * 2080 + (tj + 8 * g) * 65 + (ti + 8 * c)] = acc[c][g];
            __syncthreads();
            {
                int bl = tid >> 3, jl = tid & 7;
                float gsum[4];
                #pragma unroll
                for (int gate = 0; gate < 4; ++gate) {
                    int wrow = gate * 8 + jl;
                    float s = 0.f;
                    #pragma unroll
                    for (int s8 = 0; s8 < 8; ++s8) s += sbuf[s8 * 2080 + wrow * 65 + bl];
                    gsum[gate] = s;
                }
                float gi = gsum[0] + bs0, gf = gsum[1] + bs1;
                float gg = gsum[2] + bs2, go = gsum[3] + bs3;
                float cn = sigf(gf) * creg + sigf(gi) * tanhf(gg);
                float hn = sigf(go) * tanhf(cn);
                creg = cn;
                hnxt[(b0 + bl) * 512 + (j0 + jl)] = hn;
            }
        }
        grid.sync();
        float* tsw = hcur; hcur = hnxt; hnxt = tsw;
    }

    // ================= final out = h @ WfcT + bfc =================
    {
        hs[tid] = hcur[wg * 512 + tid];
        __syncthreads();
        int fg = tid & 31, fh = tid >> 5;   // fh 0..15 (32 h each)
        const float4* WfcT4 = (const float4*)WfcT;
        float4 acc = {0.f, 0.f, 0.f, 0.f};
        int js = fh * 32;
        #pragma unroll
        for (int jj = 0; jj < 32; ++jj) {
            float hv = hs[js + jj];
            float4 w = WfcT4[(js + jj) * 32 + fg];
            acc.x += hv * w.x; acc.y += hv * w.y; acc.z += hv * w.z; acc.w += hv * w.w;
        }
        sb4[fh * 32 + fg] = acc;
        __syncthreads();
        if (tid < 32) {
            const float4* bfc4 = (const float4*)bfc;
            float4 s = bfc4[tid];
            #pragma unroll
            for (int u = 0; u < 16; ++u) {
                float4 r = sb4[u * 32 + tid];
                s.x += r.x; s.y += r.y; s.z += r.z; s.w += r.w;
            }
            ((float4*)out)[wg * 32 + tid] = s;
        }
    }
}

extern "C" void kernel_launch(void* const* d_in, const int* in_sizes, int n_in,
                              void* d_out, int out_size, void* d_ws, size_t ws_size,
                              hipStream_t stream)
{
    const float* input  = (const float*)d_in[0];
    const float* Xmean  = (const float*)d_in[1];
    const float* Wgz    = (const float*)d_in[2];
    const float* bgz    = (const float*)d_in[3];
    const float* Wgzp   = (const float*)d_in[4];
    const float* bgzp   = (const float*)d_in[5];
    const float* Wq     = (const float*)d_in[6];
    const float* bq     = (const float*)d_in[7];
    const float* memory = (const float*)d_in[8];
    const float* Wih    = (const float*)d_in[9];
    const float* Whh    = (const float*)d_in[10];
    const float* bih    = (const float*)d_in[11];
    const float* bhh    = (const float*)d_in[12];
    const float* Wfc    = (const float*)d_in[13];
    const float* bfc    = (const float*)d_in[14];
    float* outp = (float*)d_out;

    float* ws    = (float*)d_ws;
    float* h0    = ws;                    // 131072 f
    float* h1    = h0 + 131072;           // 131072 f
    float* gdp   = h1 + 131072;           // 32768 f
    float* WfcT  = gdp + 32768;           // 65536 f
    float* bqs   = WfcT + 65536;          // 128 f
    __half* WlsTh = (__half*)(bqs + 128);         // 98304 h
    __half* memTh = (__half*)(bqs + 128 + 49152); // 65536 h
    __half* memh  = (__half*)(bqs + 128 + 49152 + 32768); // 65536 h

    hipMemsetAsync(h0, 0, 131072 * sizeof(float), stream);
    kPre<<<1473, 256, 0, stream>>>(Wq, bq, bfc, Wfc, memory, WlsTh, memTh, memh, WfcT, bqs);

    void* args[] = {
        (void*)&input, (void*)&Xmean, (void*)&Wgz, (void*)&bgz, (void*)&Wgzp, (void*)&bgzp,
        (void*)&Wih, (void*)&Whh, (void*)&bih, (void*)&bhh, (void*)&bfc,
        (void*)&h0, (void*)&h1, (void*)&gdp, (void*)&WlsTh, (void*)&memTh, (void*)&memh,
        (void*)&WfcT, (void*)&bqs, (void*)&outp
    };
    hipLaunchCooperativeKernel((void*)kMain, dim3(256), dim3(512), args, 0, stream);
}

// Round 8
// 8048.485 us; speedup vs baseline: 1.5970x; 1.1872x over previous
//
#include <hip/hip_runtime.h>
#include <hip/hip_cooperative_groups.h>
#include <hip/hip_fp16.h>
#include <cmath>

namespace cg = cooperative_groups;

#define Bsz 256
#define Tn  100
#define Fd  128
#define Hd  512
#define Od  128
#define Md  512

struct __align__(16) half8 { __half2 h2[4]; };

__device__ __forceinline__ float sigf(float x) { return 1.0f / (1.0f + __expf(-x)); }

// Precompute: WlsTh (fp16, [768][128]), bqs, memTh (fp16 [128][512]), memh (fp16 copy of memory),
// WfcT (fp32 [512][128])
__global__ void kPre(const float* __restrict__ Wq, const float* __restrict__ bq,
                     const float* __restrict__ bfc, const float* __restrict__ Wfc,
                     const float* __restrict__ memory,
                     __half* __restrict__ WlsTh, __half* __restrict__ memTh,
                     __half* __restrict__ memh,
                     float* __restrict__ WfcT, float* __restrict__ bqs)
{
    int bid = blockIdx.x, tid = threadIdx.x;
    if (bid < 768) {
        if (tid < 128) {
            int k = bid, f = tid;
            float v;
            if (k < 256) v = Wq[f * 384 + k];
            else {
                int kk = k - 256;
                float s = 0.f;
                for (int o = 0; o < 128; ++o) s += Wfc[o * 512 + kk] * Wq[f * 384 + 256 + o];
                v = s;
            }
            WlsTh[k * 128 + f] = __float2half(v);
        }
    } else if (bid == 768) {
        if (tid < 128) {
            float s = bq[tid];
            for (int o = 0; o < 128; ++o) s += bfc[o] * Wq[tid * 384 + 256 + o];
            bqs[tid] = s;
        }
    } else if (bid < 897) {
        int f = bid - 769;
        int m = tid;
        memTh[f * 512 + m] = __float2half(memory[m * 128 + f]);
        m = tid + 256;
        memTh[f * 512 + m] = __float2half(memory[m * 128 + f]);
    } else if (bid < 1409) {
        int j = bid - 897;
        if (tid < 128) WfcT[j * 128 + tid] = Wfc[tid * 512 + j];
    } else {
        int base = (bid - 1409) * 1024 + tid * 4;
        #pragma unroll
        for (int e = 0; e < 4; ++e) memh[base + e] = __float2half(memory[base + e]);
    }
}

// Persistent cooperative kernel, 256 WGs x 512 threads.
__launch_bounds__(512, 2)
__global__ void kMain(const float* __restrict__ input, const float* __restrict__ Xmean,
                      const float* __restrict__ Wgz, const float* __restrict__ bgz,
                      const float* __restrict__ Wgzp, const float* __restrict__ bgzp,
                      const float* __restrict__ Wih, const float* __restrict__ Whh,
                      const float* __restrict__ bih, const float* __restrict__ bhh,
                      const float* __restrict__ bfc,
                      float* __restrict__ h0, float* __restrict__ h1,
                      float* __restrict__ gdg,
                      const __half* __restrict__ WlsTh, const __half* __restrict__ memTh,
                      const __half* __restrict__ memh,
                      const float* __restrict__ WfcT, const float* __restrict__ bqs,
                      float* __restrict__ out)
{
    __shared__ __align__(16) float w_s[32 * 644];   // 82.4 KB
    __shared__ __align__(16) float sbuf[17408];     // 69.6 KB: phaseA red / per-wave a_s+psum
    __shared__ __align__(16) float hs[512];
    __shared__ __align__(16) float zzs[256];
    __shared__ __align__(16) float lss[128];
    __shared__ __align__(16) float scs[512];
    __shared__ __align__(16) float swred[32];

    cg::grid_group grid = cg::this_grid();
    const int tid = threadIdx.x;
    const int wg  = blockIdx.x;

    // ---- phase-B geometry: 8 waves (subgroups) x 64 lanes ----
    const int b0 = (wg >> 6) * 64;
    const int j0 = (wg & 63) * 8;
    const int sg = tid >> 6;        // wave id 0..7 (K-split, K=80 each)
    const int st = tid & 63;
    const int ti = st >> 3;         // 0..7 -> rows ti + 8c
    const int tj = st & 7;          // 0..7 -> wrows tj + 8g

    // W slice -> LDS once
    for (int idx = tid; idx < 32 * 644; idx += 512) {
        int nl = idx / 644, kk = idx - nl * 644;
        float v = 0.f;
        if (kk < 640) {
            int n = (nl >> 3) * 512 + j0 + (nl & 7);
            v = (kk < 128) ? Wih[n * 128 + kk] : Whh[n * 512 + (kk - 128)];
        }
        w_s[idx] = v;
    }

    // epilogue-thread state: one (bl, jl) pair each (512 = 64x8)
    float bs0, bs1, bs2, bs3, creg = 0.f;
    {
        int jl = tid & 7, jcol = j0 + jl;
        bs0 = bih[jcol]        + bhh[jcol];
        bs1 = bih[512 + jcol]  + bhh[512 + jcol];
        bs2 = bih[1024 + jcol] + bhh[1024 + jcol];
        bs3 = bih[1536 + jcol] + bhh[1536 + jcol];
    }
    float wvp = 0.f, bvp = 0.f;
    if (tid < 256) {
        int f = tid & 127;
        if (tid < 128) { wvp = Wgz[f * 129];  bvp = bgz[f]; }
        else           { wvp = Wgzp[f * 129]; bvp = bgzp[f]; }
    }
    __syncthreads();

    const half8* WlsTh8 = (const half8*)WlsTh;
    const half8* memTh8 = (const half8*)memTh;
    const half8* memh8  = (const half8*)memh;
    float4* sb4 = (float4*)sbuf;
    const float4* ws4 = (const float4*)w_s;

    float* hcur = h0;
    float* hnxt = h1;

    for (int t = 0; t < Tn; ++t) {
        // ================= phase A (row b = wg) =================
        hs[tid] = hcur[wg * 512 + tid];
        if (tid < 256) {
            int f = tid & 127;
            const float* basep = input + (size_t)wg * 6 * Tn * Fd + t * Fd;
            float x    = basep[0 * Tn * Fd + f];
            float mask = basep[2 * Tn * Fd + f];
            float xm   = Xmean[t * Fd + f];
            float xl, dl;
            if (tid < 128) { xl = basep[1 * Tn * Fd + f]; dl = basep[3 * Tn * Fd + f]; }
            else           { xl = basep[4 * Tn * Fd + f]; dl = basep[5 * Tn * Fd + f]; }
            float d = __expf(-fmaxf(dl * wvp + bvp, 0.f));
            zzs[tid] = mask * x + (1.f - mask) * (d * xl + (1.f - d) * xm);
        }
        __syncthreads();
        // ---- ls partials: 32 k-chunks (24 k each) x 16 f-octs ----
        {
            int fg = tid & 15, kh = tid >> 4;
            float a[8] = {0,0,0,0,0,0,0,0};
            int ks = kh * 24;
            #pragma unroll 4
            for (int kk = 0; kk < 24; ++kk) {
                int k = ks + kk;
                float v = (k < 256) ? zzs[k] : hs[k - 256];
                half8 w = WlsTh8[k * 16 + fg];
                float2 p0 = __half22float2(w.h2[0]), p1 = __half22float2(w.h2[1]);
                float2 p2 = __half22float2(w.h2[2]), p3 = __half22float2(w.h2[3]);
                a[0] += v * p0.x; a[1] += v * p0.y; a[2] += v * p1.x; a[3] += v * p1.y;
                a[4] += v * p2.x; a[5] += v * p2.y; a[6] += v * p3.x; a[7] += v * p3.y;
            }
            int base = kh * 32 + fg * 2;
            sb4[base]     = make_float4(a[0], a[1], a[2], a[3]);
            sb4[base + 1] = make_float4(a[4], a[5], a[6], a[7]);
        }
        __syncthreads();
        {
            int f = tid & 127, q = tid >> 7;
            float s = 0.f;
            #pragma unroll
            for (int u = 0; u < 8; ++u) s += sbuf[(q * 8 + u) * 128 + f];
            sbuf[8192 + q * 128 + f] = s;
        }
        __syncthreads();
        if (tid < 128)
            lss[tid] = bqs[tid] + sbuf[8192 + tid] + sbuf[8320 + tid] + sbuf[8448 + tid] + sbuf[8576 + tid];
        __syncthreads();
        // ---- scores: 8 f-chunks (16 f each) x 64 m-octs ----
        {
            int mg = tid & 63, fh = tid >> 6;
            float a[8] = {0,0,0,0,0,0,0,0};
            int fs = fh * 16;
            #pragma unroll 4
            for (int ff = 0; ff < 16; ++ff) {
                float v = lss[fs + ff];
                half8 w = memTh8[(fs + ff) * 64 + mg];
                float2 p0 = __half22float2(w.h2[0]), p1 = __half22float2(w.h2[1]);
                float2 p2 = __half22float2(w.h2[2]), p3 = __half22float2(w.h2[3]);
                a[0] += v * p0.x; a[1] += v * p0.y; a[2] += v * p1.x; a[3] += v * p1.y;
                a[4] += v * p2.x; a[5] += v * p2.y; a[6] += v * p3.x; a[7] += v * p3.y;
            }
            int base = fh * 128 + mg * 2;
            sb4[base]     = make_float4(a[0], a[1], a[2], a[3]);
            sb4[base + 1] = make_float4(a[4], a[5], a[6], a[7]);
        }
        __syncthreads();
        {
            float s = 0.f;
            #pragma unroll
            for (int u = 0; u < 8; ++u) s += sbuf[u * 512 + tid];
            scs[tid] = s;
        }
        __syncthreads();
        // ---- softmax over 512 ----
        float vsc = scs[tid];
        float mv = vsc;
        #pragma unroll
        for (int off = 32; off > 0; off >>= 1) mv = fmaxf(mv, __shfl_xor(mv, off));
        if ((tid & 63) == 0) swred[tid >> 6] = mv;
        __syncthreads();
        float mx = swred[0];
        #pragma unroll
        for (int u = 1; u < 8; ++u) mx = fmaxf(mx, swred[u]);
        float ev = __expf(vsc - mx);
        scs[tid] = ev;
        float sv = ev;
        #pragma unroll
        for (int off = 32; off > 0; off >>= 1) sv += __shfl_xor(sv, off);
        if ((tid & 63) == 0) swred[8 + (tid >> 6)] = sv;
        __syncthreads();
        float tot = 0.f;
        #pragma unroll
        for (int u = 0; u < 8; ++u) tot += swred[8 + u];
        float inv = 1.f / tot;
        // ---- gd = attn @ memory ----
        {
            int fg = tid & 15, mh = tid >> 4;
            float a[8] = {0,0,0,0,0,0,0,0};
            int ms = mh * 16;
            #pragma unroll 4
            for (int mm = 0; mm < 16; ++mm) {
                float p = scs[ms + mm];
                half8 w = memh8[(ms + mm) * 16 + fg];
                float2 p0 = __half22float2(w.h2[0]), p1 = __half22float2(w.h2[1]);
                float2 p2 = __half22float2(w.h2[2]), p3 = __half22float2(w.h2[3]);
                a[0] += p * p0.x; a[1] += p * p0.y; a[2] += p * p1.x; a[3] += p * p1.y;
                a[4] += p * p2.x; a[5] += p * p2.y; a[6] += p * p3.x; a[7] += p * p3.y;
            }
            __syncthreads();
            int base = mh * 32 + fg * 2;
            sb4[base]     = make_float4(a[0], a[1], a[2], a[3]);
            sb4[base + 1] = make_float4(a[4], a[5], a[6], a[7]);
        }
        __syncthreads();
        {
            int f = tid & 127, q = tid >> 7;
            float s = 0.f;
            #pragma unroll
            for (int u = 0; u < 8; ++u) s += sbuf[(q * 8 + u) * 128 + f];
            sbuf[8192 + q * 128 + f] = s;
        }
        __syncthreads();
        if (tid < 128)
            gdg[wg * 128 + tid] = (sbuf[8192 + tid] + sbuf[8320 + tid] + sbuf[8448 + tid] + sbuf[8576 + tid]) * inv;

        grid.sync();
        // ================= phase B (wave-private a_s; no barriers in chunk loop) =================
        {
            const float4* gdc4 = (const float4*)gdg;
            const float4* hc4  = (const float4*)hcur;
            // per-wave block: 2176 floats (544 f4). a_s = [64][5] f4; psum overwrites later.
            float4* ablk = sb4 + sg * 544;
            float acc[8][4] = {};
            #pragma unroll
            for (int cc = 0; cc < 5; ++cc) {
                // wave loads its own a-slice: 64 rows x 4 f4 (thread: rows (st>>2)+16u, quad st&3)
                #pragma unroll
                for (int u = 0; u < 4; ++u) {
                    int r = (st >> 2) + 16 * u, q = st & 3;
                    int k4 = sg * 20 + cc * 4 + q;
                    float4 v = (k4 < 32) ? gdc4[(b0 + r) * 32 + k4]
                                         : hc4[(b0 + r) * 128 + (k4 - 32)];
                    ablk[r * 5 + q] = v;
                }
                // in-wave RAW on LDS: ordered by lgkmcnt, no __syncthreads needed
                #pragma unroll
                for (int kq = 0; kq < 4; ++kq) {
                    int k4 = sg * 20 + cc * 4 + kq;
                    float4 w0 = ws4[(tj)      * 161 + k4];
                    float4 w1 = ws4[(tj + 8)  * 161 + k4];
                    float4 w2 = ws4[(tj + 16) * 161 + k4];
                    float4 w3 = ws4[(tj + 24) * 161 + k4];
                    #pragma unroll
                    for (int c = 0; c < 8; ++c) {
                        float4 a = ablk[(ti + 8 * c) * 5 + kq];
                        acc[c][0] += a.x * w0.x + a.y * w0.y + a.z * w0.z + a.w * w0.w;
                        acc[c][1] += a.x * w1.x + a.y * w1.y + a.z * w1.z + a.w * w1.w;
                        acc[c][2] += a.x * w2.x + a.y * w2.y + a.z * w2.z + a.w * w2.w;
                        acc[c][3] += a.x * w3.x + a.y * w3.y + a.z * w3.z + a.w * w3.w;
                    }
                }
            }
            // psum into own wave block: [32 wrows][68] floats (stride 68 -> 2-way max)
            float* pblk = sbuf + sg * 2176;
            #pragma unroll
            for (int c = 0; c < 8; ++c)
                #pragma unroll
                for (int g = 0; g < 4; ++g)
                    pblk[(tj + 8 * g) * 68 + (ti + 8 * c)] = acc[c][g];
            __syncthreads();
            {
                int bl = tid >> 3, jl = tid & 7;
                float gsum[4];
                #pragma unroll
                for (int gate = 0; gate < 4; ++gate) {
                    int wrow = gate * 8 + jl;
                    float s = 0.f;
                    #pragma unroll
                    for (int s8 = 0; s8 < 8; ++s8) s += sbuf[s8 * 2176 + wrow * 68 + bl];
                    gsum[gate] = s;
                }
                float gi = gsum[0] + bs0, gf = gsum[1] + bs1;
                float gg = gsum[2] + bs2, go = gsum[3] + bs3;
                float cn = sigf(gf) * creg + sigf(gi) * tanhf(gg);
                float hn = sigf(go) * tanhf(cn);
                creg = cn;
                hnxt[(b0 + bl) * 512 + (j0 + jl)] = hn;
            }
        }
        grid.sync();
        float* tsw = hcur; hcur = hnxt; hnxt = tsw;
    }

    // ================= final out = h @ WfcT + bfc =================
    {
        hs[tid] = hcur[wg * 512 + tid];
        __syncthreads();
        int fg = tid & 31, fh = tid >> 5;
        const float4* WfcT4 = (const float4*)WfcT;
        float4 acc = {0.f, 0.f, 0.f, 0.f};
        int js = fh * 32;
        #pragma unroll
        for (int jj = 0; jj < 32; ++jj) {
            float hv = hs[js + jj];
            float4 w = WfcT4[(js + jj) * 32 + fg];
            acc.x += hv * w.x; acc.y += hv * w.y; acc.z += hv * w.z; acc.w += hv * w.w;
        }
        sb4[fh * 32 + fg] = acc;
        __syncthreads();
        if (tid < 32) {
            const float4* bfc4 = (const float4*)bfc;
            float4 s = bfc4[tid];
            #pragma unroll
            for (int u = 0; u < 16; ++u) {
                float4 r = sb4[u * 32 + tid];
                s.x += r.x; s.y += r.y; s.z += r.z; s.w += r.w;
            }
            ((float4*)out)[wg * 32 + tid] = s;
        }
    }
}

extern "C" void kernel_launch(void* const* d_in, const int* in_sizes, int n_in,
                              void* d_out, int out_size, void* d_ws, size_t ws_size,
                              hipStream_t stream)
{
    const float* input  = (const float*)d_in[0];
    const float* Xmean  = (const float*)d_in[1];
    const float* Wgz    = (const float*)d_in[2];
    const float* bgz    = (const float*)d_in[3];
    const float* Wgzp   = (const float*)d_in[4];
    const float* bgzp   = (const float*)d_in[5];
    const float* Wq     = (const float*)d_in[6];
    const float* bq     = (const float*)d_in[7];
    const float* memory = (const float*)d_in[8];
    const float* Wih    = (const float*)d_in[9];
    const float* Whh    = (const float*)d_in[10];
    const float* bih    = (const float*)d_in[11];
    const float* bhh    = (const float*)d_in[12];
    const float* Wfc    = (const float*)d_in[13];
    const float* bfc    = (const float*)d_in[14];
    float* outp = (float*)d_out;

    float* ws    = (float*)d_ws;
    float* h0    = ws;                    // 131072 f
    float* h1    = h0 + 131072;           // 131072 f
    float* gdp   = h1 + 131072;           // 32768 f
    float* WfcT  = gdp + 32768;           // 65536 f
    float* bqs   = WfcT + 65536;          // 128 f
    __half* WlsTh = (__half*)(bqs + 128);
    __half* memTh = (__half*)(bqs + 128 + 49152);
    __half* memh  = (__half*)(bqs + 128 + 49152 + 32768);

    hipMemsetAsync(h0, 0, 131072 * sizeof(float), stream);
    kPre<<<1473, 256, 0, stream>>>(Wq, bq, bfc, Wfc, memory, WlsTh, memTh, memh, WfcT, bqs);

    void* args[] = {
        (void*)&input, (void*)&Xmean, (void*)&Wgz, (void*)&bgz, (void*)&Wgzp, (void*)&bgzp,
        (void*)&Wih, (void*)&Whh, (void*)&bih, (void*)&bhh, (void*)&bfc,
        (void*)&h0, (void*)&h1, (void*)&gdp, (void*)&WlsTh, (void*)&memTh, (void*)&memh,
        (void*)&WfcT, (void*)&bqs, (void*)&outp
    };
    hipLaunchCooperativeKernel((void*)kMain, dim3(256), dim3(512), args, 0, stream);
}